// Round 14
// baseline (1637.660 us; speedup 1.0000x reference)
//
#include <hip/hip_runtime.h>
#include <hip/hip_bf16.h>

// (B,C,H,G) = (4,128,8,64); F=4096, DH=16, 127 rings.
// Ring r columns are arithmetic: col_j = 63*(i0+j)+r, i0=max(0,r-63),
// j in [0, n) with n = min(r,63)-max(0,r-63)+1  (matches _build_rings).
#define Bn 4
#define Cn 128
#define Fn 4096
#define NRINGS 127

typedef short bhalf4 __attribute__((ext_vector_type(4)));
typedef float f32x4  __attribute__((ext_vector_type(4)));

// workspace offsets (float-slot units)
#define OFF_K   1048576
#define OFF_V   2097152
#define OFF_PM  3145728   // pml float2: 2 buf * 32 bh * 16 sl * 64 q = 65536 f2 = 131072 fl
#define OFF_PO  3276800   // po: * 16 d = 1048576 fl
#define OFF_VA  4325376
#define OFF_KN  4325888

__device__ __forceinline__ ushort f2bf(float f) {
    __hip_bfloat16 h = __float2bfloat16(f);
    return *reinterpret_cast<ushort*>(&h);
}

__device__ __forceinline__ int ringN(int r) {
    return (r < 64 ? r : 63) - (r > 63 ? r - 63 : 0) + 1;
}

// ---------------------------------------------------------------------------
// init (proven 47 us): Q0bf/Kbf rows [bh][col][16] bf16; Vbf transposed
// [bh][d][col] bf16. W staged in LDS (+1-padded) per 32-c chunk.
// ---------------------------------------------------------------------------
__global__ __launch_bounds__(512, 2) void initQKV(
    const float* __restrict__ x, const float* __restrict__ Wq0,
    const float* __restrict__ Wk0, const float* __restrict__ Wv0,
    ushort* __restrict__ Q0bf, ushort* __restrict__ Kbf, ushort* __restrict__ Vbf)
{
    __shared__ float xs[Cn * 64];
    __shared__ float Wls[3 * 128 * 33];
    const int wg = blockIdx.x, t = threadIdx.x;
    const int b = wg >> 6, n0 = (wg & 63) << 6;
    for (int idx = t; idx < Cn * 64; idx += 512) {
        int c = idx >> 6, j = idx & 63;
        xs[idx] = x[(size_t)((b << 7) + c) * 4096 + n0 + j];
    }
    const int o = t & 127, j0 = (t >> 7) << 4;
    float aq[16], ak[16], av[16];
#pragma unroll
    for (int k = 0; k < 16; ++k) { aq[k] = 0.f; ak[k] = 0.f; av[k] = 0.f; }
    for (int cc = 0; cc < 128; cc += 32) {
        __syncthreads();
        for (int idx = t; idx < 128 * 32; idx += 512) {
            int oo = idx >> 5, jj = idx & 31;
            Wls[oo * 33 + jj]                = Wq0[(oo << 7) + cc + jj];
            Wls[128 * 33 + oo * 33 + jj]     = Wk0[(oo << 7) + cc + jj];
            Wls[2 * 128 * 33 + oo * 33 + jj] = Wv0[(oo << 7) + cc + jj];
        }
        __syncthreads();
        for (int c2 = 0; c2 < 32; ++c2) {
            float wq = Wls[o * 33 + c2];
            float wk = Wls[128 * 33 + o * 33 + c2];
            float wv = Wls[2 * 128 * 33 + o * 33 + c2];
            const f32x4* xr4 = (const f32x4*)&xs[((cc + c2) << 6) + j0];
#pragma unroll
            for (int k4 = 0; k4 < 4; ++k4) {
                f32x4 xv = xr4[k4];
#pragma unroll
                for (int e = 0; e < 4; ++e) {
                    int k = (k4 << 2) + e;
                    aq[k] += wq * xv[e]; ak[k] += wk * xv[e]; av[k] += wv * xv[e];
                }
            }
        }
    }
    const int h = o >> 4, d = o & 15;
    const int bh = (b << 3) + h;
#pragma unroll
    for (int k = 0; k < 16; ++k) {
        int col = n0 + j0 + k;
        size_t qi = (size_t)(bh * 4096 + col) * 16 + d;
        Q0bf[qi] = f2bf(aq[k]);
        Kbf[qi]  = f2bf(ak[k]);
    }
    uint vv[8];
#pragma unroll
    for (int k2 = 0; k2 < 8; ++k2)
        vv[k2] = (uint)f2bf(av[2*k2]) | ((uint)f2bf(av[2*k2+1]) << 16);
    uint4* dst = (uint4*)&Vbf[(size_t)(bh * 16 + d) * 4096 + n0 + j0];
    dst[0] = make_uint4(vv[0], vv[1], vv[2], vv[3]);
    dst[1] = make_uint4(vv[4], vv[5], vv[6], vv[7]);
}

// ---------------------------------------------------------------------------
// Fused per-ring kernel. WG (b,h,sp of 512 keys), 512 thr.
//   - stage K/V/Q global loads -> REGISTERS at kernel top (latency hidden)
//   - combine-merge ring r-1: ALL owned cols in one unrolled pass (no
//     barriers, one latency window); pml packed float2 partials
//   - staged regs -> LDS; BAR1
//   - GEMV+patch single pass (16 col-slots x 32 tasks); BAR2
//   - MFMA flash ring r; partial stores: pml float2 + po (proven layout)
// ---------------------------------------------------------------------------
template<bool TAIL>
__global__ __launch_bounds__(512, 2) void fusedRing(
    const float* __restrict__ x, const float* __restrict__ Wk0,
    const float* __restrict__ Wv0, const ushort* __restrict__ Q0bf,
    ushort* __restrict__ Kbf, ushort* __restrict__ Vbf,
    float2* __restrict__ pml, float* __restrict__ po,
    float* __restrict__ feats, int r)
{
    __shared__ ushort Kls[512 * 24];   // 24 KB, rows 48B (2-way banks)
    __shared__ ushort Vls[16 * 520];   // 16.3 KB, V^T rows, stride 1040B
    __shared__ ushort Qls[64 * 24];    // 3 KB
    __shared__ float  outc[12 * 128];  // cnt <= 9 owned cols

    const int t = threadIdx.x, wgid = blockIdx.x;
    const int b = wgid >> 6, h = (wgid >> 3) & 7, sp = wgid & 7;
    const int bh = (b << 3) + h;
    const int keybase = sp << 9;

    const int n   = TAIL ? 0 : ringN(r);
    const int rp  = r - 1;
    const int np  = (r > 0) ? ringN(rp) : 0;
    const int i0p = (r > 0) ? (rp > 63 ? rp - 63 : 0) : 0;

    // owned j-range of prev ring within [keybase, keybase+512)
    int jlo = 0, cnt = 0;
    if (r > 0) {
        int A = keybase - rp;
        int mlo = (A > 0) ? (A + 62) / 63 : 0;           // min (i0p+j)
        int mhiN = keybase + 511 - rp;
        int mhi = (mhiN < 0) ? -1 : mhiN / 63;           // max (i0p+j)
        int jl = mlo - i0p;      if (jl < 0) jl = 0;
        int jh = mhi - i0p;      if (jh > np - 1) jh = np - 1;
        jlo = jl;
        cnt = (jh >= jl) ? (jh - jl + 1) : 0;
    }

    // ---- issue staging loads into registers (latency hides under merge) ----
    uint4 k0q, k1q, v0q, v1q, qreg;
    if (!TAIL) {
        const uint4* ks = (const uint4*)(Kbf + (size_t)((bh << 12) + keybase + t) * 16);
        k0q = ks[0]; k1q = ks[1];
        int vdd = t >> 5, vcc = t & 31;
        const uint4* vs = (const uint4*)(Vbf + (size_t)(bh * 16 + vdd) * 4096
                                         + keybase + (vcc << 4));
        v0q = vs[0]; v1q = vs[1];
        if (t < 128) {
            int q = t >> 1, half = t & 1;
            int i0F = (r > 63) ? r - 63 : 0;
            int cq = (q < n) ? (63 * (i0F + q) + r) : 0;
            qreg = *(const uint4*)(Q0bf + (size_t)((bh << 12) + cq) * 16 + half * 8);
        }
    }

    // ---- combine-merge ring r-1: all owned cols, no barriers ----
    if (r > 0 && cnt > 0) {
        const int bufp = rp & 1;
        const int slot = t >> 7, c = t & 127;
        const int hh = c >> 4, dd = c & 15;
        const int p0b = ((bufp << 5) + (b << 3) + hh) * 1024;   // + sl*64 + j
#pragma unroll
        for (int base = 0; base < 12; base += 4) {
            int ow = base + slot;
            if (ow < cnt) {
                int j = jlo + ow;
                int col = 63 * (i0p + j) + rp;
                int p0 = p0b + j;
                float2 ml[16];
                float mstar = -1e30f;
#pragma unroll
                for (int s2 = 0; s2 < 16; ++s2) {
                    ml[s2] = pml[p0 + (s2 << 6)];
                    mstar = fmaxf(mstar, ml[s2].x);
                }
                float lstar = 0.f, osum = 0.f;
#pragma unroll
                for (int s2 = 0; s2 < 16; ++s2) {
                    float e = __expf(ml[s2].x - mstar);
                    lstar += ml[s2].y * e;
                    osum  += po[(p0 + (s2 << 6)) * 16 + dd] * e;
                }
                float outv = osum / lstar + x[(size_t)((b << 7) + c) * 4096 + col];
                outc[ow * 128 + c] = outv;
                if (h == 0) feats[(size_t)((b << 7) + c) * 4096 + col] = outv;
            }
        }
    }
    if (TAIL) return;   // tail = combine/feats only

    // ---- staged regs -> LDS ----
    {
        *(uint4*)&Kls[t * 24]     = k0q;
        *(uint4*)&Kls[t * 24 + 8] = k1q;
        int vdd = t >> 5, vcc = t & 31;
        *(uint4*)&Vls[vdd * 520 + (vcc << 4)]     = v0q;
        *(uint4*)&Vls[vdd * 520 + (vcc << 4) + 8] = v1q;
        if (t < 128) {
            int q = t >> 1, half = t & 1;
            *(uint4*)&Qls[q * 24 + half * 8] = qreg;
        }
    }
    __syncthreads();   // BAR1: outc + staged LDS visible

    // ---- GEMV + patch, single pass (16 col-slots x 32 tasks) ----
    if (cnt > 0) {
        int slot = t >> 5, task = t & 31;
        if (slot < cnt) {
            int j = jlo + slot;
            int col = 63 * (i0p + j) + rp;
            int isV = task >> 4, dd = task & 15;
            int row = (h << 4) + dd;
            const float* W = isV ? Wv0 : Wk0;
            const float* oc = &outc[slot * 128];
            float acc = 0.f;
            for (int c2 = 0; c2 < Cn; ++c2)
                acc += W[(row << 7) + c2] * oc[c2];
            ushort bfv = f2bf(acc);
            if (isV) {
                Vbf[(size_t)(bh * 16 + dd) * 4096 + col] = bfv;
                Vls[dd * 520 + (col - keybase)] = bfv;
            } else {
                Kbf[(size_t)((bh << 12) + col) * 16 + dd] = bfv;
                Kls[(col - keybase) * 24 + dd] = bfv;
            }
        }
    }
    __syncthreads();   // BAR2: patches visible

    // ---- MFMA flash ring r ----
    const int w = t >> 6, lane = t & 63;
    const int qt = w & 3, kh = w >> 2;
    const int buf = r & 1;
    if (qt * 16 < n) {
        const int lm = lane & 15, lg = lane >> 4;
        bhalf4 qf = *(const bhalf4*)&Qls[(qt * 16 + lm) * 24 + (lg << 2)];
        const int key0 = kh << 8;
        f32x4 sc[16];
#pragma unroll
        for (int kt = 0; kt < 16; ++kt) {
            bhalf4 kf = *(const bhalf4*)&Kls[(key0 + (kt << 4) + lm) * 24 + (lg << 2)];
            f32x4 z = {0.f, 0.f, 0.f, 0.f};
            sc[kt] = __builtin_amdgcn_mfma_f32_16x16x16bf16_1k(kf, qf, z, 0, 0, 0);
        }
        float m = -1e30f;
#pragma unroll
        for (int kt = 0; kt < 16; ++kt)
            m = fmaxf(m, fmaxf(fmaxf(sc[kt][0], sc[kt][1]), fmaxf(sc[kt][2], sc[kt][3])));
        m = fmaxf(m, __shfl_xor(m, 16));
        m = fmaxf(m, __shfl_xor(m, 32));
        float lsum = 0.f;
        f32x4 oacc = {0.f, 0.f, 0.f, 0.f};
#pragma unroll
        for (int kt = 0; kt < 16; ++kt) {
            float p0 = __expf((sc[kt][0] - m) * 0.25f);
            float p1 = __expf((sc[kt][1] - m) * 0.25f);
            float p2 = __expf((sc[kt][2] - m) * 0.25f);
            float p3 = __expf((sc[kt][3] - m) * 0.25f);
            lsum += (p0 + p1) + (p2 + p3);
            bhalf4 pv;
            pv[0] = (short)f2bf(p0); pv[1] = (short)f2bf(p1);
            pv[2] = (short)f2bf(p2); pv[3] = (short)f2bf(p3);
            bhalf4 vf = *(const bhalf4*)&Vls[lm * 520 + key0 + (kt << 4) + (lg << 2)];
            oacc = __builtin_amdgcn_mfma_f32_16x16x16bf16_1k(pv, vf, oacc, 0, 0, 0);
        }
        lsum += __shfl_xor(lsum, 16);
        lsum += __shfl_xor(lsum, 32);
        const int pb = ((((buf << 5) + bh) << 4) | ((sp << 1) + kh)) * 64;
        if (lg == 0)
            pml[pb + qt * 16 + lm] = make_float2(m * 0.25f, lsum);
#pragma unroll
        for (int reg = 0; reg < 4; ++reg)
            po[(pb + qt * 16 + (lg << 2) + reg) * 16 + lm] = oacc[reg];
    }
}

// ---------------------------------------------------------------------------
// Epilogue 1: Va = Wv0@anchor_feats, Kn = head-normalize(Wk1@anchor_feats)
// ---------------------------------------------------------------------------
__global__ __launch_bounds__(128) void epi1(
    const float* __restrict__ feats, const float* __restrict__ Wv0,
    const float* __restrict__ Wk1, const int* __restrict__ rings,
    float* __restrict__ Va, float* __restrict__ Kn)
{
    int b = blockIdx.x;
    int i = threadIdx.x;
    int anchor = rings[0];
    __shared__ float la[128];
    __shared__ float kk2[128];
    la[i] = feats[(size_t)((b << 7) + i) * 4096 + anchor];
    __syncthreads();
    float va = 0.f, k1 = 0.f;
    for (int c = 0; c < 128; ++c) {
        va += Wv0[i * 128 + c] * la[c];
        k1 += Wk1[i * 128 + c] * la[c];
    }
    Va[b * 128 + i] = va;
    kk2[i] = k1 * k1;
    __syncthreads();
    float ss = 0.f;
    int hb = i & ~15;
    for (int d = 0; d < 16; ++d) ss += kk2[hb + d];
    Kn[b * 128 + i] = k1 * rsqrtf(ss + 1e-8f);
}

// ---------------------------------------------------------------------------
// Epilogue 2: reg-tiled, W^T staged in LDS once per block.
// ---------------------------------------------------------------------------
__global__ __launch_bounds__(256) void epi2(
    const float* __restrict__ x, const float* __restrict__ Wq1,
    const float* __restrict__ Va, const float* __restrict__ Kn,
    float* __restrict__ scores)
{
    __shared__ float Wt[128 * 132];
    __shared__ float lxT[128 * 36];
    const int bid = blockIdx.x, t = threadIdx.x;
    const int b = bid >> 7, col0 = (bid & 127) << 5;
    for (int idx = t; idx < 128 * 128; idx += 256) {
        int o = idx >> 7, c = idx & 127;
        Wt[c*132 + o] = Wq1[idx];
    }
    for (int idx = t; idx < 128 * 32; idx += 256) {
        int c = idx >> 5, col = idx & 31;
        lxT[c*36 + col] = x[(size_t)((b << 7) + c) * 4096 + col0 + col] + Va[(b << 7) + c];
    }
    __syncthreads();
    const int og = t & 31, colg = t >> 5;
    const int o0 = og << 2, cl0 = colg << 2;
    float acc[4][4];
#pragma unroll
    for (int i = 0; i < 4; ++i)
#pragma unroll
        for (int j = 0; j < 4; ++j) acc[i][j] = 0.f;
    for (int c = 0; c < 128; ++c) {
        f32x4 wv = *(const f32x4*)&Wt[c*132 + o0];
        f32x4 xv = *(const f32x4*)&lxT[c*36 + cl0];
#pragma unroll
        for (int i = 0; i < 4; ++i)
#pragma unroll
            for (int j = 0; j < 4; ++j) acc[i][j] += wv[i] * xv[j];
    }
    float kn4[4];
#pragma unroll
    for (int i = 0; i < 4; ++i) kn4[i] = Kn[(b << 7) + o0 + i];
    float res[4];
#pragma unroll
    for (int j = 0; j < 4; ++j) {
        float ss = acc[0][j]*acc[0][j] + acc[1][j]*acc[1][j]
                 + acc[2][j]*acc[2][j] + acc[3][j]*acc[3][j];
        ss += __shfl_xor(ss, 1);
        ss += __shfl_xor(ss, 2);
        float rs = rsqrtf(ss + 1e-8f);
        float mp = (acc[0][j]*kn4[0] + acc[1][j]*kn4[1]
                  + acc[2][j]*kn4[2] + acc[3][j]*kn4[3]) * rs;
#pragma unroll
        for (int msk = 1; msk <= 16; msk <<= 1) mp += __shfl_xor(mp, msk);
        res[j] = 0.5f + mp * (1.0f / 16.0f);
    }
    if (og == 0) {
#pragma unroll
        for (int j = 0; j < 4; ++j)
            scores[(b << 12) + col0 + cl0 + j] = res[j];
    }
}

// ---------------------------------------------------------------------------
// Launcher: 1 init + 127 rings + 1 tail + 2 epilogues = 131 launches.
// ---------------------------------------------------------------------------
extern "C" void kernel_launch(void* const* d_in, const int* in_sizes, int n_in,
                              void* d_out, int out_size, void* d_ws, size_t ws_size,
                              hipStream_t stream) {
    const float* x   = (const float*)d_in[0];
    const float* Wq0 = (const float*)d_in[1];
    const float* Wk0 = (const float*)d_in[2];
    const float* Wv0 = (const float*)d_in[3];
    const float* Wq1 = (const float*)d_in[4];
    const float* Wk1 = (const float*)d_in[5];
    const int*   rings = (const int*)d_in[6];

    float* feats  = (float*)d_out;                 // (B,C,F)
    float* scores = feats + Bn * Cn * Fn;          // (B,F)

    float*  ws   = (float*)d_ws;
    ushort* Q0bf = (ushort*)ws;
    ushort* Kbf  = (ushort*)(ws + OFF_K);
    ushort* Vbf  = (ushort*)(ws + OFF_V);
    float2* pml  = (float2*)(ws + OFF_PM);
    float*  po   = ws + OFF_PO;
    float*  Va   = ws + OFF_VA;
    float*  Kn   = ws + OFF_KN;

    initQKV<<<256, 512, 0, stream>>>(x, Wq0, Wk0, Wv0, Q0bf, Kbf, Vbf);

    for (int r = 0; r < NRINGS; ++r) {
        fusedRing<false><<<256, 512, 0, stream>>>(
            x, Wk0, Wv0, Q0bf, Kbf, Vbf, pml, po, feats, r);
    }
    fusedRing<true><<<256, 512, 0, stream>>>(
        x, Wk0, Wv0, Q0bf, Kbf, Vbf, pml, po, feats, NRINGS);

    epi1<<<Bn, 128, 0, stream>>>(feats, Wv0, Wk1, rings, Va, Kn);
    epi2<<<512, 256, 0, stream>>>(x, Wq1, Va, Kn, scores);
}